// Round 9
// baseline (216.920 us; speedup 1.0000x reference)
//
#include <hip/hip_runtime.h>
#include <hip/hip_bf16.h>

#define NPOS 6272          // 8*28*28
#define NT   98            // NPOS/64
#define CIN  256
#define CR   32
#define BATCH 2
// QSCALE * log2(e): scores come out in log2 units -> softmax uses raw exp2
#define QS2  0.25503371989518595f
#define PPITCH 72          // P^T LDS row pitch (shorts): 144B, 16B-aligned

typedef short bf16x8s __attribute__((ext_vector_type(8)));  // 8 bf16 = 4 VGPR
typedef short short4v __attribute__((ext_vector_type(4)));  // 4 bf16 = 8B
typedef float f32x4   __attribute__((ext_vector_type(4)));
typedef unsigned short ushort_t;

__device__ __forceinline__ ushort_t f2bf(float f) {        // RNE fp32->bf16
    unsigned u = __builtin_bit_cast(unsigned, f);
    u += 0x7fff + ((u >> 16) & 1);
    return (ushort_t)(u >> 16);
}
__device__ __forceinline__ float bf2f(ushort_t h) {
    return __builtin_bit_cast(float, (unsigned)h << 16);
}

// ---------------------------------------------------------------------------
// Kernel 1: Q/K/V projections (round-7 form: 8 scalar w-loads per channel
// keeps live SGPRs small; round-8's 128-per-chunk overflowed the SGPR file).
// grid (NT, B, 3); block 256 = 4 waves; wave g computes rows 8g..8g+7.
// ---------------------------------------------------------------------------
__global__ __launch_bounds__(256) void qkv_kernel(
    const float* __restrict__ x, const float* __restrict__ qw,
    const float* __restrict__ kw, const float* __restrict__ vw,
    ushort_t* __restrict__ Qh, ushort_t* __restrict__ Ql,
    ushort_t* __restrict__ Kh, ushort_t* __restrict__ Kl,
    ushort_t* __restrict__ Vt)
{
    const int b   = blockIdx.y;
    const int z   = blockIdx.z;
    const int nl  = threadIdx.x & 63;
    const int n   = blockIdx.x * 64 + nl;
    const int g   = __builtin_amdgcn_readfirstlane(threadIdx.x >> 6); // 0..3
    const float* w  = (z == 0) ? qw : (z == 1) ? kw : vw;
    const float* xb = x + (size_t)b * CIN * NPOS + n;

    float acc[8];
#pragma unroll
    for (int i = 0; i < 8; ++i) acc[i] = 0.f;
#pragma unroll 8
    for (int c = 0; c < CIN; ++c) {
        float xv = xb[(size_t)c * NPOS];
#pragma unroll
        for (int i = 0; i < 8; ++i)
            acc[i] += w[(g * 8 + i) * CIN + c] * xv;   // wave-uniform -> smem
    }
    if (z == 2) {                                // V -> transposed [32][N]
#pragma unroll
        for (int i = 0; i < 8; ++i)
            Vt[((size_t)b * CR + g * 8 + i) * NPOS + n] = f2bf(acc[i]);
    } else {
        ushort_t* dh = (z == 0) ? Qh : Kh;
        ushort_t* dl = (z == 0) ? Ql : Kl;
        float s = (z == 0) ? QS2 : 1.0f;         // fold softmax scale into Q
        bf16x8s fh, fl;
#pragma unroll
        for (int i = 0; i < 8; ++i) {
            float v = acc[i] * s;
            ushort_t h = f2bf(v);
            fh[i] = (short)h;
            fl[i] = (short)f2bf(v - bf2f(h));    // residual
        }
        size_t off = ((size_t)b * NPOS + n) * CR + g * 8;
        *(bf16x8s*)(dh + off) = fh;
        *(bf16x8s*)(dl + off) = fl;
    }
}

// ---------------------------------------------------------------------------
// Kernel 2: MFMA flash attention, TRANSPOSED scores (S^T = K·Q^T), with an
// EXPLICIT software pipeline: next iteration's K/V tile is loaded into a
// second register tile BEFORE the current tile's softmax/PV chain (round-8
// showed the compiler won't hoist on its own: VGPR stayed 64).
// grid (196, S, B); block 64 = 1 wave owning 32 queries.
// ---------------------------------------------------------------------------
struct KVTile {
    bf16x8s kh[4], kl[4], vb[4];                 // vb[k2*2+c]
};

__device__ __forceinline__ KVTile load_tile(
    const ushort_t* __restrict__ Khb, const ushort_t* __restrict__ Klb,
    const ushort_t* __restrict__ Vtb, int j0, int col, int quad)
{
    KVTile t;
#pragma unroll
    for (int f = 0; f < 4; ++f) {
        t.kh[f] = *(const bf16x8s*)(Khb + (size_t)(j0 + f * 16 + col) * CR + quad * 8);
        t.kl[f] = *(const bf16x8s*)(Klb + (size_t)(j0 + f * 16 + col) * CR + quad * 8);
    }
#pragma unroll
    for (int k2 = 0; k2 < 2; ++k2)
#pragma unroll
        for (int c = 0; c < 2; ++c)
            t.vb[k2 * 2 + c] = *(const bf16x8s*)(
                Vtb + (size_t)(c * 16 + col) * NPOS + j0 + k2 * 32 + quad * 8);
    return t;
}

__device__ __forceinline__ void compute_tile(
    const KVTile& t, const bf16x8s* qbh, const bf16x8s* qbl,
    f32x4 (&oc)[2][2], float (&m_)[2], float (&l_)[2],
    ushort_t* pb, int col, int quad)
{
    f32x4 z4 = {0.f, 0.f, 0.f, 0.f};
#pragma unroll
    for (int h = 0; h < 2; ++h) {
        f32x4 sc[4];                             // S^T: key=f*16+quad*4+r, q=col
#pragma unroll
        for (int f = 0; f < 4; ++f) {
            sc[f] = __builtin_amdgcn_mfma_f32_16x16x32_bf16(t.kl[f], qbh[h], z4, 0, 0, 0);
            sc[f] = __builtin_amdgcn_mfma_f32_16x16x32_bf16(t.kh[f], qbl[h], sc[f], 0, 0, 0);
            sc[f] = __builtin_amdgcn_mfma_f32_16x16x32_bf16(t.kh[f], qbh[h], sc[f], 0, 0, 0);
        }
        float v0 = fmaxf(fmaxf(sc[0][0], sc[0][1]), fmaxf(sc[0][2], sc[0][3]));
        float v1 = fmaxf(fmaxf(sc[1][0], sc[1][1]), fmaxf(sc[1][2], sc[1][3]));
        float v2 = fmaxf(fmaxf(sc[2][0], sc[2][1]), fmaxf(sc[2][2], sc[2][3]));
        float v3 = fmaxf(fmaxf(sc[3][0], sc[3][1]), fmaxf(sc[3][2], sc[3][3]));
        float v  = fmaxf(fmaxf(v0, v1), fmaxf(v2, v3));
        v = fmaxf(v, __shfl_xor(v, 16));
        v = fmaxf(v, __shfl_xor(v, 32));
        float mo = m_[h];
        if (__any(v > mo)) {                     // wave-uniform skip (~90% skip
            float mn = fmaxf(mo, v);             //  after the max stabilizes)
            float al = __builtin_amdgcn_exp2f(mo - mn);
            l_[h] *= al;
#pragma unroll
            for (int r = 0; r < 4; ++r) { oc[h][0][r] *= al; oc[h][1][r] *= al; }
            m_[h] = mn;
        }
        float mn = m_[h];
        float lsum = 0.f;
#pragma unroll
        for (int f = 0; f < 4; ++f) {
            float p0 = __builtin_amdgcn_exp2f(sc[f][0] - mn);
            float p1 = __builtin_amdgcn_exp2f(sc[f][1] - mn);
            float p2 = __builtin_amdgcn_exp2f(sc[f][2] - mn);
            float p3 = __builtin_amdgcn_exp2f(sc[f][3] - mn);
            lsum += (p0 + p1) + (p2 + p3);
            short4v pk;
            pk[0] = (short)f2bf(p0); pk[1] = (short)f2bf(p1);
            pk[2] = (short)f2bf(p2); pk[3] = (short)f2bf(p3);
            *(short4v*)(&pb[h * 16 * PPITCH + col * PPITCH + f * 16 + quad * 4]) = pk;
        }
        l_[h] += lsum;
    }
    // PV: O^T += V^T · P^T (per-wave LDS; same-wave DS ops are in-order)
#pragma unroll
    for (int h = 0; h < 2; ++h) {
#pragma unroll
        for (int k2 = 0; k2 < 2; ++k2) {
            bf16x8s pbo = *(const bf16x8s*)(
                &pb[h * 16 * PPITCH + col * PPITCH + k2 * 32 + quad * 8]);
            oc[h][0] = __builtin_amdgcn_mfma_f32_16x16x32_bf16(t.vb[k2 * 2 + 0], pbo, oc[h][0], 0, 0, 0);
            oc[h][1] = __builtin_amdgcn_mfma_f32_16x16x32_bf16(t.vb[k2 * 2 + 1], pbo, oc[h][1], 0, 0, 0);
        }
    }
}

template <int ITERS>
__global__ __launch_bounds__(64, 3) void attn_kernel(
    const ushort_t* __restrict__ Qh, const ushort_t* __restrict__ Ql,
    const ushort_t* __restrict__ Kh, const ushort_t* __restrict__ Kl,
    const ushort_t* __restrict__ Vt, ushort_t* __restrict__ Opart,
    float* __restrict__ Mp, float* __restrict__ Lp)
{
    __shared__ __align__(16) ushort_t pbuf[2 * 16 * PPITCH];

    const int lane = threadIdx.x;
    const int col  = lane & 15;                  // query (local)
    const int quad = lane >> 4;                  // 0..3
    const int b    = blockIdx.z;
    const int s    = blockIdx.y;
    const int qw0  = blockIdx.x * 32;
    ushort_t* pb   = pbuf;

    const ushort_t* Qhb = Qh + (size_t)b * NPOS * CR;
    const ushort_t* Qlb = Ql + (size_t)b * NPOS * CR;
    const ushort_t* Khb = Kh + (size_t)b * NPOS * CR;
    const ushort_t* Klb = Kl + (size_t)b * NPOS * CR;
    const ushort_t* Vtb = Vt + (size_t)b * CR * NPOS;

    bf16x8s qbh[2], qbl[2];                      // Q as B-operand
    qbh[0] = *(const bf16x8s*)(Qhb + (size_t)(qw0 + col) * CR + quad * 8);
    qbh[1] = *(const bf16x8s*)(Qhb + (size_t)(qw0 + 16 + col) * CR + quad * 8);
    qbl[0] = *(const bf16x8s*)(Qlb + (size_t)(qw0 + col) * CR + quad * 8);
    qbl[1] = *(const bf16x8s*)(Qlb + (size_t)(qw0 + 16 + col) * CR + quad * 8);

    f32x4 oc[2][2];
#pragma unroll
    for (int h = 0; h < 2; ++h)
#pragma unroll
        for (int c = 0; c < 2; ++c)
#pragma unroll
            for (int r = 0; r < 4; ++r) oc[h][c][r] = 0.f;
    float m_[2] = { -1e30f, -1e30f };
    float l_[2] = { 0.f, 0.f };

    if constexpr (ITERS <= 14) {                 // pipelined, fully unrolled
        KVTile cur = load_tile(Khb, Klb, Vtb, s * ITERS * 64, col, quad);
#pragma unroll
        for (int it = 0; it < ITERS; ++it) {
            KVTile nxt = cur;                    // dead copy unless overwritten
            if (it + 1 < ITERS)
                nxt = load_tile(Khb, Klb, Vtb, (s * ITERS + it + 1) * 64, col, quad);
            compute_tile(cur, qbh, qbl, oc, m_, l_, pb, col, quad);
            cur = nxt;
        }
    } else {                                     // fallback: plain loop
        for (int it = 0; it < ITERS; ++it) {
            KVTile cur = load_tile(Khb, Klb, Vtb, (s * ITERS + it) * 64, col, quad);
            compute_tile(cur, qbh, qbl, oc, m_, l_, pb, col, quad);
        }
    }

    // Finish l: reduce per-lane partials across quads (same q = same col).
#pragma unroll
    for (int h = 0; h < 2; ++h) {
        float l = l_[h];
        l += __shfl_xor(l, 16);
        l += __shfl_xor(l, 32);
        l_[h] = l;
    }

    const size_t sb = (size_t)(s * BATCH + b);
    ushort_t* Ob = Opart + sb * CR * NPOS;
#pragma unroll
    for (int h = 0; h < 2; ++h)
#pragma unroll
        for (int c = 0; c < 2; ++c)
#pragma unroll
            for (int r = 0; r < 4; ++r) {
                int ch = c * 16 + quad * 4 + r;
                Ob[(size_t)ch * NPOS + qw0 + h * 16 + col] = f2bf(oc[h][c][r]);
            }
    if (quad == 0) {                             // 16 lanes own the 16 q's
#pragma unroll
        for (int h = 0; h < 2; ++h) {
            Mp[sb * NPOS + qw0 + h * 16 + col] = m_[h];
            Lp[sb * NPOS + qw0 + h * 16 + col] = l_[h];
        }
    }
}

// ---------------------------------------------------------------------------
// Kernel 3: FUSED merge (log-sum-exp over key-splits) + out-projection +
// residual. One wave = 64 positions, fully autonomous (no barriers):
// LSE weights + O-merge in registers, then 64 channels of projection.
// grid (NT, B, 4): z picks channel quarter c0=z*64 (stage A redundant x4,
// buys 784 blocks of occupancy). Kills the Omrg round-trip + one launch.
// ---------------------------------------------------------------------------
template <int S_>
__global__ __launch_bounds__(64, 4) void mergeproj_kernel(
    const ushort_t* __restrict__ Opart, const float* __restrict__ Mp,
    const float* __restrict__ Lp, const float* __restrict__ ow,
    const float* __restrict__ x, float* __restrict__ y)
{
    const int b  = blockIdx.y;
    const int z  = blockIdx.z;
    const int n  = blockIdx.x * 64 + threadIdx.x;

    float mg = -1e30f;
#pragma unroll
    for (int s = 0; s < S_; ++s)
        mg = fmaxf(mg, Mp[(size_t)(s * BATCH + b) * NPOS + n]);
    float wseg[S_];
    float lg = 0.f;
#pragma unroll
    for (int s = 0; s < S_; ++s) {
        size_t sb = (size_t)(s * BATCH + b);
        float w = __builtin_amdgcn_exp2f(Mp[sb * NPOS + n] - mg);
        wseg[s] = w;
        lg += w * Lp[sb * NPOS + n];
    }
    float inv = 1.f / lg;

    float o[CR];
#pragma unroll
    for (int r = 0; r < CR; ++r) o[r] = 0.f;
#pragma unroll
    for (int s = 0; s < S_; ++s) {
        const ushort_t* Ob = Opart + (size_t)(s * BATCH + b) * CR * NPOS + n;
        float ov[CR];
#pragma unroll
        for (int r = 0; r < CR; ++r)             // 32 coalesced loads in flight
            ov[r] = bf2f(Ob[(size_t)r * NPOS]);
#pragma unroll
        for (int r = 0; r < CR; ++r) o[r] += wseg[s] * ov[r];
    }
#pragma unroll
    for (int r = 0; r < CR; ++r) o[r] *= inv;

    const float* xb = x + (size_t)b * CIN * NPOS + n;
    float*       yb = y + (size_t)b * CIN * NPOS + n;
    const int c0 = z * 64;
#pragma unroll 8
    for (int cc = 0; cc < 64; ++cc) {
        int c = c0 + cc;                         // loop-uniform -> s_loads
        float acc = xb[(size_t)c * NPOS];
#pragma unroll
        for (int r = 0; r < CR; ++r) acc += ow[c * CR + r] * o[r];
        yb[(size_t)c * NPOS] = acc;
    }
}

// ---------------------------------------------------------------------------
extern "C" void kernel_launch(void* const* d_in, const int* in_sizes, int n_in,
                              void* d_out, int out_size, void* d_ws, size_t ws_size,
                              hipStream_t stream)
{
    const float* x  = (const float*)d_in[0];
    const float* qw = (const float*)d_in[1];
    const float* kw = (const float*)d_in[2];
    const float* vw = (const float*)d_in[3];
    const float* ow = (const float*)d_in[4];
    float* out = (float*)d_out;

    const size_t qkvN = (size_t)BATCH * CR * NPOS;   // 401,408 elements
    // S must divide 98 (=6272/64) so every split is whole 64-key iters.
    const int s_cand[4] = {14, 7, 2, 1};
    int S = 1;
    for (int i = 0; i < 4; ++i) {
        int Sc = s_cand[i];
        size_t need = 5 * qkvN * sizeof(ushort_t)            // Qh,Ql,Kh,Kl,Vt
                    + (size_t)Sc * qkvN * sizeof(ushort_t)   // Opart
                    + 2 * (size_t)Sc * BATCH * NPOS * sizeof(float); // M,L
        if (need <= ws_size) { S = Sc; break; }
    }
    ushort_t* Qh = (ushort_t*)d_ws;
    ushort_t* Ql = Qh + qkvN;
    ushort_t* Kh = Ql + qkvN;
    ushort_t* Kl = Kh + qkvN;
    ushort_t* Vt = Kl + qkvN;
    ushort_t* Op = Vt + qkvN;
    float* Mp    = (float*)(Op + (size_t)S * qkvN);
    float* Lp    = Mp + (size_t)S * BATCH * NPOS;

    qkv_kernel<<<dim3(NT, BATCH, 3), 256, 0, stream>>>(x, qw, kw, vw,
                                                       Qh, Ql, Kh, Kl, Vt);
    dim3 ag(196, S, BATCH);
    switch (S) {
        case 14: attn_kernel<7> <<<ag, 64, 0, stream>>>(Qh, Ql, Kh, Kl, Vt, Op, Mp, Lp); break;
        case 7:  attn_kernel<14><<<ag, 64, 0, stream>>>(Qh, Ql, Kh, Kl, Vt, Op, Mp, Lp); break;
        case 2:  attn_kernel<49><<<ag, 64, 0, stream>>>(Qh, Ql, Kh, Kl, Vt, Op, Mp, Lp); break;
        default: attn_kernel<98><<<ag, 64, 0, stream>>>(Qh, Ql, Kh, Kl, Vt, Op, Mp, Lp); break;
    }
    dim3 mp(NT, BATCH, 4);
    switch (S) {
        case 14: mergeproj_kernel<14><<<mp, 64, 0, stream>>>(Op, Mp, Lp, ow, x, out); break;
        case 7:  mergeproj_kernel<7> <<<mp, 64, 0, stream>>>(Op, Mp, Lp, ow, x, out); break;
        case 2:  mergeproj_kernel<2> <<<mp, 64, 0, stream>>>(Op, Mp, Lp, ow, x, out); break;
        default: mergeproj_kernel<1> <<<mp, 64, 0, stream>>>(Op, Mp, Lp, ow, x, out); break;
    }
}

// Round 10
// 144.314 us; speedup vs baseline: 1.5031x; 1.5031x over previous
//
#include <hip/hip_runtime.h>
#include <hip/hip_bf16.h>

#define NPOS 6272          // 8*28*28
#define NT   98            // NPOS/64
#define CIN  256
#define CR   32
#define BATCH 2
// QSCALE * log2(e): scores come out in log2 units -> softmax uses raw exp2
#define QS2  0.25503371989518595f
#define PPITCH 72          // P^T LDS row pitch (shorts): 144B, 16B-aligned

typedef short bf16x8s __attribute__((ext_vector_type(8)));  // 8 bf16 = 4 VGPR
typedef short short4v __attribute__((ext_vector_type(4)));  // 4 bf16 = 8B
typedef float f32x4   __attribute__((ext_vector_type(4)));
typedef unsigned short ushort_t;

__device__ __forceinline__ ushort_t f2bf(float f) {        // RNE fp32->bf16
    unsigned u = __builtin_bit_cast(unsigned, f);
    u += 0x7fff + ((u >> 16) & 1);
    return (ushort_t)(u >> 16);
}
__device__ __forceinline__ float bf2f(ushort_t h) {
    return __builtin_bit_cast(float, (unsigned)h << 16);
}

// ---------------------------------------------------------------------------
// Kernel 1: Q/K/V projections (round-7 form — best measured; 8 scalar w-loads
// per channel stays within the SGPR budget, unlike the R8/R9 big batches).
// grid (NT, B, 3); block 256 = 4 waves; wave g computes rows 8g..8g+7.
// ---------------------------------------------------------------------------
__global__ __launch_bounds__(256) void qkv_kernel(
    const float* __restrict__ x, const float* __restrict__ qw,
    const float* __restrict__ kw, const float* __restrict__ vw,
    ushort_t* __restrict__ Qh, ushort_t* __restrict__ Ql,
    ushort_t* __restrict__ Kh, ushort_t* __restrict__ Kl,
    ushort_t* __restrict__ Vt)
{
    const int b   = blockIdx.y;
    const int z   = blockIdx.z;
    const int nl  = threadIdx.x & 63;
    const int n   = blockIdx.x * 64 + nl;
    const int g   = __builtin_amdgcn_readfirstlane(threadIdx.x >> 6); // 0..3
    const float* w  = (z == 0) ? qw : (z == 1) ? kw : vw;
    const float* xb = x + (size_t)b * CIN * NPOS + n;

    float acc[8];
#pragma unroll
    for (int i = 0; i < 8; ++i) acc[i] = 0.f;
#pragma unroll 8
    for (int c = 0; c < CIN; ++c) {
        float xv = xb[(size_t)c * NPOS];
#pragma unroll
        for (int i = 0; i < 8; ++i)
            acc[i] += w[(g * 8 + i) * CIN + c] * xv;   // wave-uniform -> smem
    }
    if (z == 2) {                                // V -> transposed [32][N]
#pragma unroll
        for (int i = 0; i < 8; ++i)
            Vt[((size_t)b * CR + g * 8 + i) * NPOS + n] = f2bf(acc[i]);
    } else {
        ushort_t* dh = (z == 0) ? Qh : Kh;
        ushort_t* dl = (z == 0) ? Ql : Kl;
        float s = (z == 0) ? QS2 : 1.0f;         // fold softmax scale into Q
        bf16x8s fh, fl;
#pragma unroll
        for (int i = 0; i < 8; ++i) {
            float v = acc[i] * s;
            ushort_t h = f2bf(v);
            fh[i] = (short)h;
            fl[i] = (short)f2bf(v - bf2f(h));    // residual
        }
        size_t off = ((size_t)b * NPOS + n) * CR + g * 8;
        *(bf16x8s*)(dh + off) = fh;
        *(bf16x8s*)(dl + off) = fl;
    }
}

// ---------------------------------------------------------------------------
// Kernel 2: MFMA flash attention, TRANSPOSED scores (S^T = K·Q^T), with an
// explicit register prefetch of the next K/V tile.
//  - individual vector arrays + per-element rotation under FULL unroll
//    (R9's struct copy lowered to scratch: WRITE_SIZE 12->78 MB, VGPR 84);
//  - __launch_bounds__(128,2): VGPR cap 256 (two tiles ~160 regs live, no
//    spill) at the de-facto occupancy R8 already ran (28% ~ 2.25 w/SIMD).
// grid (98, S, B); block 128 = 2 independent waves (private pbuf halves).
// ---------------------------------------------------------------------------
__device__ __forceinline__ void load_tile(
    const ushort_t* __restrict__ Khb, const ushort_t* __restrict__ Klb,
    const ushort_t* __restrict__ Vtb, int j0, int col, int quad,
    bf16x8s* kh, bf16x8s* kl, bf16x8s* vb)
{
#pragma unroll
    for (int f = 0; f < 4; ++f) {
        kh[f] = *(const bf16x8s*)(Khb + (size_t)(j0 + f * 16 + col) * CR + quad * 8);
        kl[f] = *(const bf16x8s*)(Klb + (size_t)(j0 + f * 16 + col) * CR + quad * 8);
    }
#pragma unroll
    for (int k2 = 0; k2 < 2; ++k2)
#pragma unroll
        for (int c = 0; c < 2; ++c)
            vb[k2 * 2 + c] = *(const bf16x8s*)(
                Vtb + (size_t)(c * 16 + col) * NPOS + j0 + k2 * 32 + quad * 8);
}

__device__ __forceinline__ void compute_tile(
    const bf16x8s* kh, const bf16x8s* kl, const bf16x8s* vb,
    const bf16x8s* qbh, const bf16x8s* qbl,
    f32x4 (&oc)[2][2], float (&m_)[2], float (&l_)[2],
    ushort_t* pb, int col, int quad)
{
    f32x4 z4 = {0.f, 0.f, 0.f, 0.f};
#pragma unroll
    for (int h = 0; h < 2; ++h) {
        f32x4 sc[4];                             // S^T: key=f*16+quad*4+r, q=col
#pragma unroll
        for (int f = 0; f < 4; ++f) {
            sc[f] = __builtin_amdgcn_mfma_f32_16x16x32_bf16(kl[f], qbh[h], z4, 0, 0, 0);
            sc[f] = __builtin_amdgcn_mfma_f32_16x16x32_bf16(kh[f], qbl[h], sc[f], 0, 0, 0);
            sc[f] = __builtin_amdgcn_mfma_f32_16x16x32_bf16(kh[f], qbh[h], sc[f], 0, 0, 0);
        }
        float v0 = fmaxf(fmaxf(sc[0][0], sc[0][1]), fmaxf(sc[0][2], sc[0][3]));
        float v1 = fmaxf(fmaxf(sc[1][0], sc[1][1]), fmaxf(sc[1][2], sc[1][3]));
        float v2 = fmaxf(fmaxf(sc[2][0], sc[2][1]), fmaxf(sc[2][2], sc[2][3]));
        float v3 = fmaxf(fmaxf(sc[3][0], sc[3][1]), fmaxf(sc[3][2], sc[3][3]));
        float v  = fmaxf(fmaxf(v0, v1), fmaxf(v2, v3));
        v = fmaxf(v, __shfl_xor(v, 16));
        v = fmaxf(v, __shfl_xor(v, 32));
        float mo = m_[h];
        float mn = fmaxf(mo, v);
        float al = __builtin_amdgcn_exp2f(mo - mn);      // lane-uniform per q
        float lsum = 0.f;
#pragma unroll
        for (int f = 0; f < 4; ++f) {
            float p0 = __builtin_amdgcn_exp2f(sc[f][0] - mn);
            float p1 = __builtin_amdgcn_exp2f(sc[f][1] - mn);
            float p2 = __builtin_amdgcn_exp2f(sc[f][2] - mn);
            float p3 = __builtin_amdgcn_exp2f(sc[f][3] - mn);
            lsum += (p0 + p1) + (p2 + p3);
            short4v pk;
            pk[0] = (short)f2bf(p0); pk[1] = (short)f2bf(p1);
            pk[2] = (short)f2bf(p2); pk[3] = (short)f2bf(p3);
            *(short4v*)(&pb[h * 16 * PPITCH + col * PPITCH + f * 16 + quad * 4]) = pk;
        }
        m_[h] = mn;
        l_[h] = l_[h] * al + lsum;
#pragma unroll
        for (int r = 0; r < 4; ++r) { oc[h][0][r] *= al; oc[h][1][r] *= al; }
    }
    // PV: O^T += V^T · P^T (per-wave LDS; same-wave DS ops are in-order)
#pragma unroll
    for (int h = 0; h < 2; ++h) {
#pragma unroll
        for (int k2 = 0; k2 < 2; ++k2) {
            bf16x8s pbo = *(const bf16x8s*)(
                &pb[h * 16 * PPITCH + col * PPITCH + k2 * 32 + quad * 8]);
            oc[h][0] = __builtin_amdgcn_mfma_f32_16x16x32_bf16(vb[k2 * 2 + 0], pbo, oc[h][0], 0, 0, 0);
            oc[h][1] = __builtin_amdgcn_mfma_f32_16x16x32_bf16(vb[k2 * 2 + 1], pbo, oc[h][1], 0, 0, 0);
        }
    }
}

template <int ITERS>
__global__ __launch_bounds__(128, 2) void attn_kernel(
    const ushort_t* __restrict__ Qh, const ushort_t* __restrict__ Ql,
    const ushort_t* __restrict__ Kh, const ushort_t* __restrict__ Kl,
    const ushort_t* __restrict__ Vt, ushort_t* __restrict__ Opart,
    float* __restrict__ Mp, float* __restrict__ Lp)
{
    __shared__ __align__(16) ushort_t pbuf[2 * 2 * 16 * PPITCH];

    const int lane = threadIdx.x & 63;
    const int wv   = threadIdx.x >> 6;           // 0..1
    const int col  = lane & 15;                  // query (local)
    const int quad = lane >> 4;                  // 0..3
    const int b    = blockIdx.z;
    const int s    = blockIdx.y;
    const int qw0  = blockIdx.x * 64 + wv * 32;
    ushort_t* pb   = &pbuf[wv * 2 * 16 * PPITCH];

    const ushort_t* Qhb = Qh + (size_t)b * NPOS * CR;
    const ushort_t* Qlb = Ql + (size_t)b * NPOS * CR;
    const ushort_t* Khb = Kh + (size_t)b * NPOS * CR;
    const ushort_t* Klb = Kl + (size_t)b * NPOS * CR;
    const ushort_t* Vtb = Vt + (size_t)b * CR * NPOS;

    bf16x8s qbh[2], qbl[2];                      // Q as B-operand
    qbh[0] = *(const bf16x8s*)(Qhb + (size_t)(qw0 + col) * CR + quad * 8);
    qbh[1] = *(const bf16x8s*)(Qhb + (size_t)(qw0 + 16 + col) * CR + quad * 8);
    qbl[0] = *(const bf16x8s*)(Qlb + (size_t)(qw0 + col) * CR + quad * 8);
    qbl[1] = *(const bf16x8s*)(Qlb + (size_t)(qw0 + 16 + col) * CR + quad * 8);

    f32x4 oc[2][2];
#pragma unroll
    for (int h = 0; h < 2; ++h)
#pragma unroll
        for (int c = 0; c < 2; ++c)
#pragma unroll
            for (int r = 0; r < 4; ++r) oc[h][c][r] = 0.f;
    float m_[2] = { -1e30f, -1e30f };
    float l_[2] = { 0.f, 0.f };

    if constexpr (ITERS <= 14) {
        // Explicit software pipeline, fully unrolled: rotation is SSA-renamed.
        bf16x8s ckh[4], ckl[4], cvb[4], nkh[4], nkl[4], nvb[4];
        load_tile(Khb, Klb, Vtb, s * ITERS * 64, col, quad, ckh, ckl, cvb);
#pragma unroll
        for (int it = 0; it < ITERS; ++it) {
            if (it + 1 < ITERS)
                load_tile(Khb, Klb, Vtb, (s * ITERS + it + 1) * 64, col, quad,
                          nkh, nkl, nvb);
            compute_tile(ckh, ckl, cvb, qbh, qbl, oc, m_, l_, pb, col, quad);
            if (it + 1 < ITERS) {
#pragma unroll
                for (int f = 0; f < 4; ++f) {
                    ckh[f] = nkh[f]; ckl[f] = nkl[f]; cvb[f] = nvb[f];
                }
            }
        }
    } else {                                     // fallback: plain loop
        for (int it = 0; it < ITERS; ++it) {
            bf16x8s kh[4], kl[4], vb[4];
            load_tile(Khb, Klb, Vtb, (s * ITERS + it) * 64, col, quad, kh, kl, vb);
            compute_tile(kh, kl, vb, qbh, qbl, oc, m_, l_, pb, col, quad);
        }
    }

    // Finish l: reduce per-lane partials across quads (same q = same col).
#pragma unroll
    for (int h = 0; h < 2; ++h) {
        float l = l_[h];
        l += __shfl_xor(l, 16);
        l += __shfl_xor(l, 32);
        l_[h] = l;
    }

    const size_t sb = (size_t)(s * BATCH + b);
    ushort_t* Ob = Opart + sb * CR * NPOS;
#pragma unroll
    for (int h = 0; h < 2; ++h)
#pragma unroll
        for (int c = 0; c < 2; ++c)
#pragma unroll
            for (int r = 0; r < 4; ++r) {
                int ch = c * 16 + quad * 4 + r;
                Ob[(size_t)ch * NPOS + qw0 + h * 16 + col] = f2bf(oc[h][c][r]);
            }
    if (quad == 0) {                             // 16 lanes own the 16 q's
#pragma unroll
        for (int h = 0; h < 2; ++h) {
            Mp[sb * NPOS + qw0 + h * 16 + col] = m_[h];
            Lp[sb * NPOS + qw0 + h * 16 + col] = l_[h];
        }
    }
}

// ---------------------------------------------------------------------------
// Kernel 3: merge key-splits (log-sum-exp) -> Omrg [B][32][N] fp32.
// (round-7 version, measured good) grid (NT, B, 8): wave g handles ch r=z*4+g.
// ---------------------------------------------------------------------------
template <int S_>
__global__ __launch_bounds__(256) void merge_kernel(
    const ushort_t* __restrict__ Opart, const float* __restrict__ Mp,
    const float* __restrict__ Lp, float* __restrict__ Omrg)
{
    const int b  = blockIdx.y;
    const int z  = blockIdx.z;
    const int nl = threadIdx.x & 63;
    const int n  = blockIdx.x * 64 + nl;
    const int g  = __builtin_amdgcn_readfirstlane(threadIdx.x >> 6);
    const int r  = z * 4 + g;

    float mg = -1e30f;
#pragma unroll
    for (int s = 0; s < S_; ++s)
        mg = fmaxf(mg, Mp[(size_t)(s * BATCH + b) * NPOS + n]);
    float lg = 0.f, acc = 0.f;
#pragma unroll
    for (int s = 0; s < S_; ++s) {
        size_t sb = (size_t)(s * BATCH + b);
        float w = __builtin_amdgcn_exp2f(Mp[sb * NPOS + n] - mg);
        lg  += w * Lp[sb * NPOS + n];
        acc += w * bf2f(Opart[(sb * CR + r) * NPOS + n]);   // coalesced
    }
    Omrg[((size_t)b * CR + r) * NPOS + n] = acc / lg;
}

// ---------------------------------------------------------------------------
// Kernel 4: output projection + residual (round-7 version, measured good).
// grid (NT, B, 8), block 256: wave g handles 8 channels c in [z*32+8g, +8).
// ---------------------------------------------------------------------------
__global__ __launch_bounds__(256) void proj_kernel(
    const float* __restrict__ Omrg, const float* __restrict__ ow,
    const float* __restrict__ x, float* __restrict__ y)
{
    const int b  = blockIdx.y;
    const int z  = blockIdx.z;
    const int nl = threadIdx.x & 63;
    const int n  = blockIdx.x * 64 + nl;
    const int g  = __builtin_amdgcn_readfirstlane(threadIdx.x >> 6);

    float o[CR];
#pragma unroll
    for (int r = 0; r < CR; ++r)
        o[r] = Omrg[((size_t)b * CR + r) * NPOS + n];

    const float* xb = x + (size_t)b * CIN * NPOS + n;
    float*       yb = y + (size_t)b * CIN * NPOS + n;
    const int c0 = z * 32 + g * 8;
#pragma unroll
    for (int cc = 0; cc < 8; ++cc) {
        int c = c0 + cc;                          // wave-uniform
        float acc = xb[(size_t)c * NPOS];
#pragma unroll
        for (int r = 0; r < CR; ++r) acc += ow[c * CR + r] * o[r];
        yb[(size_t)c * NPOS] = acc;
    }
}

// ---------------------------------------------------------------------------
extern "C" void kernel_launch(void* const* d_in, const int* in_sizes, int n_in,
                              void* d_out, int out_size, void* d_ws, size_t ws_size,
                              hipStream_t stream)
{
    const float* x  = (const float*)d_in[0];
    const float* qw = (const float*)d_in[1];
    const float* kw = (const float*)d_in[2];
    const float* vw = (const float*)d_in[3];
    const float* ow = (const float*)d_in[4];
    float* out = (float*)d_out;

    const size_t qkvN = (size_t)BATCH * CR * NPOS;   // 401,408 elements
    // S must divide 98 (=6272/64) so every split is whole 64-key iters.
    const int s_cand[4] = {14, 7, 2, 1};
    int S = 1;
    for (int i = 0; i < 4; ++i) {
        int Sc = s_cand[i];
        size_t need = 5 * qkvN * sizeof(ushort_t)            // Qh,Ql,Kh,Kl,Vt
                    + qkvN * sizeof(float)                   // Omrg
                    + (size_t)Sc * qkvN * sizeof(ushort_t)   // Opart
                    + 2 * (size_t)Sc * BATCH * NPOS * sizeof(float); // M,L
        if (need <= ws_size) { S = Sc; break; }
    }
    ushort_t* Qh = (ushort_t*)d_ws;
    ushort_t* Ql = Qh + qkvN;
    ushort_t* Kh = Ql + qkvN;
    ushort_t* Kl = Kh + qkvN;
    ushort_t* Vt = Kl + qkvN;
    float* Omrg  = (float*)(Vt + qkvN);
    ushort_t* Op = (ushort_t*)(Omrg + qkvN);
    float* Mp    = (float*)(Op + (size_t)S * qkvN);
    float* Lp    = Mp + (size_t)S * BATCH * NPOS;

    qkv_kernel<<<dim3(NT, BATCH, 3), 256, 0, stream>>>(x, qw, kw, vw,
                                                       Qh, Ql, Kh, Kl, Vt);
    dim3 ag(NT, S, BATCH);
    switch (S) {
        case 14: attn_kernel<7> <<<ag, 128, 0, stream>>>(Qh, Ql, Kh, Kl, Vt, Op, Mp, Lp); break;
        case 7:  attn_kernel<14><<<ag, 128, 0, stream>>>(Qh, Ql, Kh, Kl, Vt, Op, Mp, Lp); break;
        case 2:  attn_kernel<49><<<ag, 128, 0, stream>>>(Qh, Ql, Kh, Kl, Vt, Op, Mp, Lp); break;
        default: attn_kernel<98><<<ag, 128, 0, stream>>>(Qh, Ql, Kh, Kl, Vt, Op, Mp, Lp); break;
    }
    dim3 mg(NT, BATCH, 8);
    switch (S) {
        case 14: merge_kernel<14><<<mg, 256, 0, stream>>>(Op, Mp, Lp, Omrg); break;
        case 7:  merge_kernel<7> <<<mg, 256, 0, stream>>>(Op, Mp, Lp, Omrg); break;
        case 2:  merge_kernel<2> <<<mg, 256, 0, stream>>>(Op, Mp, Lp, Omrg); break;
        default: merge_kernel<1> <<<mg, 256, 0, stream>>>(Op, Mp, Lp, Omrg); break;
    }
    proj_kernel<<<dim3(NT, BATCH, 8), 256, 0, stream>>>(Omrg, ow, x, out);
}